// Round 6
// baseline (130.468 us; speedup 1.0000x reference)
//
#include <hip/hip_runtime.h>

// YOLO loss, single fused kernel (last-block-done reduction).
// R1: same-line atomics serialize -> two-stage plain stores (219->38us).
// R2: 120B-stride loads -> LDS tile staging (38->35us).
// R3: best so far (35.3us); latency-bound, not BW-bound.
// R4: inline classify regressed (43.8us) -> VALU bloat, occupancy not binding.
// R5 lesson: compiler SANK the batched reg-staging loads (VGPR stayed 44) ->
//    source-level MLP defeated. This round:
//    (a) global_load_lds async staging (guaranteed back-to-back issue, no VGPR
//        round trip, drained once by the barrier's vmcnt(0)),
//    (b) unconditional tcls/tbox reg prefetch (can't be sunk past the barrier),
//    (c) fuse stage-2 via last-block-done (threadfence + device atomic ctr),
//        killing the 2nd launch + serial final kernel.
//
// d_in[0] pred_tensor  f32 [N,S,S,30]
// d_in[1] target_boxes f32 [N,S,S,4]
// d_in[2] target_cls   f32 [N,S,S,20]
// d_in[3] has_object_map bool -> int32 [N,S,S]
// d_out: (total, reg, contain, noobj, cls) f32[5]

namespace {
constexpr float kLCoord = 5.0f;
constexpr float kLNoobj = 0.5f;
constexpr float kInvS   = 1.0f / 14.0f;
constexpr int   kTile   = 256;    // cells per block; 802816 = 3136*256 exact
}

__device__ __forceinline__ void async_cp16(const float4* g, float4* l) {
  __builtin_amdgcn_global_load_lds(
      (const __attribute__((address_space(1))) void*)g,
      (__attribute__((address_space(3))) void*)l,
      16, 0, 0);
}

__global__ __launch_bounds__(256, 5) void yolo_fused_kernel(
    const float* __restrict__ pred,
    const float* __restrict__ tbox,
    const float* __restrict__ tcls,
    const int*   __restrict__ mask,
    float* __restrict__ ws,
    unsigned*   __restrict__ ctr,
    float* __restrict__ out,
    int ncells, int nblocks)
{
  __shared__ float4 lds_pred4[kTile * 30 / 4];   // 1920 f4 = 30 KB, linear (required by global_load_lds)
  __shared__ float  lds_maskf[kTile];            // 1 KB
  __shared__ float  red[4][4];
  __shared__ int    is_last;

  const int tid  = threadIdx.x;
  const long base = (long)blockIdx.x * kTile;

  // valid/clamp handling (no-op for this problem's exact tiling, kept for safety)
  const long cell    = base + tid;
  const bool valid   = (cell < ncells);
  const long cellc   = valid ? cell : (ncells - 1);
  const long maxf4p  = ((long)ncells * 30) / 4 - 1;   // last valid pred f4
  const long maxf4c  = ((long)ncells * 20) / 4 - 1;   // last valid tcls f4

  // ---- own-cell mask (coalesced) ----
  const int m_reg = valid ? mask[cellc] : 0;
  lds_maskf[tid] = (float)m_reg;

  // ---- async stage pred tile: 1920 f4 via global_load_lds (8 issues, no VGPRs) ----
  const float4* src4 = reinterpret_cast<const float4*>(pred) + base * 30 / 4;
  const long sbase = base * 30 / 4;
#pragma unroll
  for (int k = 0; k < 7; ++k) {
    const long i = tid + (long)k * 256;
    const long gi = (sbase + i <= maxf4p) ? i : (maxf4p - sbase);
    async_cp16(src4 + gi, lds_pred4 + i);
  }
  if (tid < 128) {   // wave-uniform: waves 0,1 only (1920 = 7.5*256)
    const long i = tid + 1792;
    const long gi = (sbase + i <= maxf4p) ? i : (maxf4p - sbase);
    async_cp16(src4 + gi, lds_pred4 + i);
  }

  // ---- unconditional reg prefetch: tbox + 5 tcls f4 (coalesced, clamped) ----
  float4 tb = reinterpret_cast<const float4*>(tbox)[cellc];
  const float4* tc4p = reinterpret_cast<const float4*>(tcls);
  const long cbase = base * 5;
#define TCIDX(K) (cbase + tid + (K) * 256 <= maxf4c ? cbase + tid + (K) * 256 : maxf4c)
  float4 t0 = tc4p[TCIDX(0)];
  float4 t1 = tc4p[TCIDX(1)];
  float4 t2 = tc4p[TCIDX(2)];
  float4 t3 = tc4p[TCIDX(3)];
  float4 t4 = tc4p[TCIDX(4)];
#undef TCIDX

  __syncthreads();   // drains vmcnt(0): pred tile + mask in LDS, prefetches landed

  float cls_l = 0.f, noobj_l = 0.f, reg_l = 0.f, cont_l = 0.f;

  // ---- Phase B: per-cell box/IoU (thread t <-> cell base+t) ----
  {
    const float2* lp2 = reinterpret_cast<const float2*>(
        reinterpret_cast<const float*>(lds_pred4) + tid * 30);
    float pb[10];
#pragma unroll
    for (int i = 0; i < 5; ++i) {
      float2 v = lp2[i];
      pb[2 * i]     = v.x;
      pb[2 * i + 1] = v.y;
    }

    if (!m_reg) {
      if (valid) noobj_l = pb[4] * pb[4] + pb[9] * pb[9];
    } else {
      float tcx = tb.x * kInvS, tcy = tb.y * kInvS;
      float tx1 = tcx - 0.5f * tb.z;
      float ty1 = tcy - 0.5f * tb.w;
      float tx2 = tcx + 0.5f * tb.z;
      float ty2 = tcy + 0.5f * tb.w;
      float ta  = (tx2 - tx1) * (ty2 - ty1);

      float iou0, iou1;
#pragma unroll
      for (int b = 0; b < 2; ++b) {
        float qw = pb[5 * b + 2], qh = pb[5 * b + 3];
        float cx = pb[5 * b + 0] * kInvS, cy = pb[5 * b + 1] * kInvS;
        float px1 = cx - 0.5f * qw, py1 = cy - 0.5f * qh;
        float px2 = cx + 0.5f * qw, py2 = cy + 0.5f * qh;
        float lx = fmaxf(px1, tx1), ly = fmaxf(py1, ty1);
        float rx = fminf(px2, tx2), ry = fminf(py2, ty2);
        float w = fmaxf(rx - lx, 0.f), h = fmaxf(ry - ly, 0.f);
        float inter = w * h;
        float pa = (px2 - px1) * (py2 - py1);
        float v = inter / (pa + ta - inter);
        if (b == 0) iou0 = v; else iou1 = v;
      }

      // jnp.argmax -> first max on tie: box1 only on STRICT greater
      const bool sel = (iou1 > iou0);
      float biou = fmaxf(iou0, iou1);
      float bx = sel ? pb[5] : pb[0];
      float by = sel ? pb[6] : pb[1];
      float bw = sel ? pb[7] : pb[2];
      float bh = sel ? pb[8] : pb[3];
      float bc = sel ? pb[9] : pb[4];

      float dx = bx - tb.x, dy = by - tb.y;
      float dw = sqrtf(bw) - sqrtf(tb.z);
      float dh = sqrtf(bh) - sqrtf(tb.w);
      reg_l = dx * dx + dy * dy + dw * dw + dh * dh;   // *L_COORD at the end

      float dc = bc - biou;
      cont_l = dc * dc;
    }
  }

  // ---- Phase C: cls loss, element-parallel, branchless (x maskf) ----
  {
    const float* lp = reinterpret_cast<const float*>(lds_pred4);
#define PHASE_C(K, TK)                                                         \
    { const int i  = tid + (K << 8);                                           \
      const int cl = i / 5;                                                    \
      const int q  = i - cl * 5;                                               \
      const float mf = lds_maskf[cl];                                          \
      const float2* a = reinterpret_cast<const float2*>(lp + cl * 30 + 10 + (q << 2)); \
      float2 a0 = a[0], a1 = a[1];                                             \
      float c0 = a0.x - TK.x;                                                  \
      float c1 = a0.y - TK.y;                                                  \
      float c2 = a1.x - TK.z;                                                  \
      float c3 = a1.y - TK.w;                                                  \
      cls_l += mf * (c0 * c0 + c1 * c1 + c2 * c2 + c3 * c3); }
    PHASE_C(0, t0) PHASE_C(1, t1) PHASE_C(2, t2) PHASE_C(3, t3) PHASE_C(4, t4)
#undef PHASE_C
  }

  // ---- wave64 reduction ----
#pragma unroll
  for (int off = 32; off > 0; off >>= 1) {
    cls_l   += __shfl_down(cls_l,   off, 64);
    noobj_l += __shfl_down(noobj_l, off, 64);
    reg_l   += __shfl_down(reg_l,   off, 64);
    cont_l  += __shfl_down(cont_l,  off, 64);
  }

  const int lane = tid & 63;
  const int wid  = tid >> 6;
  if (lane == 0) {
    red[wid][0] = cls_l;
    red[wid][1] = noobj_l;
    red[wid][2] = reg_l;
    red[wid][3] = cont_l;
  }
  __syncthreads();

  if (tid == 0) {
    float c = 0.f, n = 0.f, r = 0.f, t = 0.f;
#pragma unroll
    for (int w = 0; w < 4; ++w) {
      c += red[w][0];
      n += red[w][1];
      r += red[w][2];
      t += red[w][3];
    }
    reinterpret_cast<float4*>(ws)[blockIdx.x] = make_float4(c, n, r, t);
    __threadfence();                       // release: partial visible device-wide
    unsigned old = atomicAdd(ctr, 1u);     // device-scope
    is_last = (old == (unsigned)(nblocks - 1)) ? 1 : 0;
  }
  __syncthreads();

  // ---- last block: final reduction + output ----
  if (is_last) {
    __threadfence();                       // acquire: see all partials
    float c = 0.f, n = 0.f, r = 0.f, t = 0.f;
#pragma unroll 4
    for (int i = tid; i < nblocks; i += 256) {
      float4 v = reinterpret_cast<const float4*>(ws)[i];
      c += v.x;
      n += v.y;
      r += v.z;
      t += v.w;
    }
#pragma unroll
    for (int off = 32; off > 0; off >>= 1) {
      c += __shfl_down(c, off, 64);
      n += __shfl_down(n, off, 64);
      r += __shfl_down(r, off, 64);
      t += __shfl_down(t, off, 64);
    }
    if (lane == 0) {
      red[wid][0] = c;
      red[wid][1] = n;
      red[wid][2] = r;
      red[wid][3] = t;
    }
    __syncthreads();
    if (tid == 0) {
      float cc = 0.f, nn = 0.f, rr = 0.f, tt = 0.f;
#pragma unroll
      for (int w = 0; w < 4; ++w) {
        cc += red[w][0];
        nn += red[w][1];
        rr += red[w][2];
        tt += red[w][3];
      }
      nn *= kLNoobj;
      rr *= kLCoord;
      out[0] = cc + nn + rr + tt;  // total
      out[1] = rr;                 // reg_loss
      out[2] = tt;                 // contain_loss
      out[3] = nn;                 // no_obj_loss
      out[4] = cc;                 // cls_loss
    }
  }
}

extern "C" void kernel_launch(void* const* d_in, const int* in_sizes, int n_in,
                              void* d_out, int out_size, void* d_ws, size_t ws_size,
                              hipStream_t stream) {
  const float* pred = (const float*)d_in[0];
  const float* tbox = (const float*)d_in[1];
  const float* tcls = (const float*)d_in[2];
  const int*   mask = (const int*)d_in[3];
  float* out = (float*)d_out;
  float* ws  = (float*)d_ws;

  const int ncells  = in_sizes[3];                 // N*S*S (802816)
  const int nblocks = (ncells + kTile - 1) / kTile;

  // counter lives in d_ws past the partials, 256B-aligned; zeroed every call
  size_t ctr_off = (((size_t)nblocks * sizeof(float4)) + 255) & ~(size_t)255;
  unsigned* ctr = (unsigned*)((char*)d_ws + ctr_off);
  hipMemsetAsync(ctr, 0, sizeof(unsigned), stream);

  yolo_fused_kernel<<<nblocks, 256, 0, stream>>>(pred, tbox, tcls, mask, ws, ctr,
                                                 out, ncells, nblocks);
}

// Round 7
// 34.760 us; speedup vs baseline: 3.7534x; 3.7534x over previous
//
#include <hip/hip_runtime.h>

// YOLO loss, two-stage reduction (R3 structure) + async global_load_lds staging.
// R1: same-line atomics serialize -> two-stage plain stores (219->38us).
// R2: 120B-stride loads -> LDS tile staging (38->35us).
// R3: best so far (35.3us); latency-bound, not BW-bound.
// R4: inline per-float classify regressed (43.8us) -> VALU bloat.
// R5: source-level reg batching sunk by compiler (VGPR stayed 44) -> neutral.
// R6 lesson: fused last-block tail = 3136 same-line device atomics + threadfence
//    => +106us pure serialization (replays 172us at ~0 FETCH). NEVER fuse the
//    tail via single-counter atomics on this chip. global_load_lds unindicted.
// R7: R3 + global_load_lds(16B) staging ONLY. One change, isolated.
//
// d_in[0] pred_tensor  f32 [N,S,S,30]
// d_in[1] target_boxes f32 [N,S,S,4]
// d_in[2] target_cls   f32 [N,S,S,20]
// d_in[3] has_object_map bool -> int32 [N,S,S]
// d_out: (total, reg, contain, noobj, cls) f32[5]

namespace {
constexpr float kLCoord = 5.0f;
constexpr float kLNoobj = 0.5f;
constexpr float kInvS   = 1.0f / 14.0f;
constexpr int   kTile   = 256;    // cells per block; 802816 = 3136*256 exact
}

__device__ __forceinline__ void async_cp16(const float4* g, float4* l) {
  __builtin_amdgcn_global_load_lds(
      (const __attribute__((address_space(1))) void*)g,
      (__attribute__((address_space(3))) void*)l,
      16, 0, 0);
}

__global__ __launch_bounds__(256) void yolo_partial_kernel(
    const float* __restrict__ pred,
    const float* __restrict__ tbox,
    const float* __restrict__ tcls,
    const int*   __restrict__ mask,
    float* __restrict__ ws,
    int ncells)
{
  __shared__ float lds_pred[kTile * 30];   // 30 KB linear, cell-major (global_load_lds needs linear)
  __shared__ int   lds_mask[kTile];        // 1 KB
  __shared__ float red[4][4];

  const int tid  = threadIdx.x;
  const int base = blockIdx.x * kTile;
  const int tile_cells = min(kTile, ncells - base);

  float cls_l = 0.f, noobj_l = 0.f, reg_l = 0.f, cont_l = 0.f;

  // ---- Phase A0: mask to LDS (coalesced) ----
  const int m_reg = (tid < tile_cells) ? mask[base + tid] : 0;
  lds_mask[tid] = m_reg;

  // ---- Phase A1: async stage pred tile (1920 float4 = 30KB) ----
  // 7 full wave-rounds + half round (waves 0-1). All issued back-to-back,
  // no VGPR round-trip; the barrier's vmcnt(0) drains once.
  {
    const float4* src4 = reinterpret_cast<const float4*>(pred + (long)base * 30);
    float4* dst4 = reinterpret_cast<float4*>(lds_pred);
    if (tile_cells == kTile) {           // block-uniform fast path (always, here)
#pragma unroll
      for (int k = 0; k < 7; ++k)
        async_cp16(src4 + (tid + k * 256), dst4 + (tid + k * 256));
      if (tid < 128)                      // waves 0,1 whole: wave-uniform LDS base
        async_cp16(src4 + (tid + 1792), dst4 + (tid + 1792));
    } else {
      const int nfl = tile_cells * 30;
      const int nf4 = nfl >> 2;
      for (int i = tid; i < nf4; i += 256) dst4[i] = src4[i];
      for (int f = (nf4 << 2) + tid; f < nfl; f += 256)
        lds_pred[f] = pred[(long)base * 30 + f];
    }
  }
  __syncthreads();   // drains vmcnt(0) + lgkm: pred tile + mask visible

  // ---- Phase B: per-cell box/IoU math (thread t <-> cell base+t) ----
  if (tid < tile_cells) {
    const float2* lp2 = reinterpret_cast<const float2*>(lds_pred + tid * 30);
    float pb[10];
#pragma unroll
    for (int i = 0; i < 5; ++i) {
      float2 v = lp2[i];
      pb[2 * i]     = v.x;
      pb[2 * i + 1] = v.y;
    }

    if (!m_reg) {
      noobj_l = pb[4] * pb[4] + pb[9] * pb[9];
    } else {
      float4 tb = *(reinterpret_cast<const float4*>(tbox) + (long)(base + tid));
      float tcx = tb.x * kInvS, tcy = tb.y * kInvS;
      float tx1 = tcx - 0.5f * tb.z;
      float ty1 = tcy - 0.5f * tb.w;
      float tx2 = tcx + 0.5f * tb.z;
      float ty2 = tcy + 0.5f * tb.w;
      float ta  = (tx2 - tx1) * (ty2 - ty1);

      float iou0, iou1;
#pragma unroll
      for (int b = 0; b < 2; ++b) {
        float qw = pb[5 * b + 2], qh = pb[5 * b + 3];
        float cx = pb[5 * b + 0] * kInvS, cy = pb[5 * b + 1] * kInvS;
        float px1 = cx - 0.5f * qw, py1 = cy - 0.5f * qh;
        float px2 = cx + 0.5f * qw, py2 = cy + 0.5f * qh;
        float lx = fmaxf(px1, tx1), ly = fmaxf(py1, ty1);
        float rx = fminf(px2, tx2), ry = fminf(py2, ty2);
        float w = fmaxf(rx - lx, 0.f), h = fmaxf(ry - ly, 0.f);
        float inter = w * h;
        float pa = (px2 - px1) * (py2 - py1);
        float v = inter / (pa + ta - inter);
        if (b == 0) iou0 = v; else iou1 = v;
      }

      // jnp.argmax -> first max on tie: box1 only on STRICT greater
      const bool sel = (iou1 > iou0);
      float biou = fmaxf(iou0, iou1);
      float bx = sel ? pb[5] : pb[0];
      float by = sel ? pb[6] : pb[1];
      float bw = sel ? pb[7] : pb[2];
      float bh = sel ? pb[8] : pb[3];
      float bc = sel ? pb[9] : pb[4];

      float dx = bx - tb.x, dy = by - tb.y;
      float dw = sqrtf(bw) - sqrtf(tb.z);
      float dh = sqrtf(bh) - sqrtf(tb.w);
      reg_l = dx * dx + dy * dy + dw * dw + dh * dh;   // *L_COORD in stage 2

      float dc = bc - biou;
      cont_l = dc * dc;
    }
  }

  // ---- Phase C: cls loss, element-parallel over the tile's tcls float4s ----
  // f4 index i in [0, tile_cells*5): cell = i/5, channels 10+4*(i%5)..+3.
  {
    const float4* tc = reinterpret_cast<const float4*>(tcls) + (long)base * 5;
    const int nf4 = tile_cells * 5;           // 1280 when full
#pragma unroll
    for (int k = 0; k < 5; ++k) {
      const int i = tid + (k << 8);
      if (i < nf4) {
        const int cl = i / 5;
        if (lds_mask[cl]) {                   // same-word broadcast across 5 lanes
          float4 t = tc[i];
          const float2* lp2 =
              reinterpret_cast<const float2*>(lds_pred + cl * 30 + 10 + ((i - cl * 5) << 2));
          float2 a0 = lp2[0], a1 = lp2[1];
          float c0 = a0.x - t.x;
          float c1 = a0.y - t.y;
          float c2 = a1.x - t.z;
          float c3 = a1.y - t.w;
          cls_l += c0 * c0 + c1 * c1 + c2 * c2 + c3 * c3;
        }
      }
    }
  }

  // ---- wave64 reduction ----
#pragma unroll
  for (int off = 32; off > 0; off >>= 1) {
    cls_l   += __shfl_down(cls_l,   off, 64);
    noobj_l += __shfl_down(noobj_l, off, 64);
    reg_l   += __shfl_down(reg_l,   off, 64);
    cont_l  += __shfl_down(cont_l,  off, 64);
  }

  const int lane = tid & 63;
  const int wid  = tid >> 6;
  if (lane == 0) {
    red[wid][0] = cls_l;
    red[wid][1] = noobj_l;
    red[wid][2] = reg_l;
    red[wid][3] = cont_l;
  }
  __syncthreads();

  if (tid == 0) {
    float c = 0.f, n = 0.f, r = 0.f, t = 0.f;
#pragma unroll
    for (int w = 0; w < 4; ++w) {
      c += red[w][0];
      n += red[w][1];
      r += red[w][2];
      t += red[w][3];
    }
    *(reinterpret_cast<float4*>(ws) + blockIdx.x) = make_float4(c, n, r, t);
  }
}

__global__ __launch_bounds__(256) void yolo_final_kernel(
    const float* __restrict__ ws, int nparts, float* __restrict__ out)
{
  float c = 0.f, n = 0.f, r = 0.f, t = 0.f;
  for (int i = threadIdx.x; i < nparts; i += 256) {
    float4 v = *(reinterpret_cast<const float4*>(ws) + i);
    c += v.x;
    n += v.y;
    r += v.z;
    t += v.w;
  }

#pragma unroll
  for (int off = 32; off > 0; off >>= 1) {
    c += __shfl_down(c, off, 64);
    n += __shfl_down(n, off, 64);
    r += __shfl_down(r, off, 64);
    t += __shfl_down(t, off, 64);
  }

  __shared__ float red[4][4];
  const int lane = threadIdx.x & 63;
  const int wid  = threadIdx.x >> 6;
  if (lane == 0) {
    red[wid][0] = c;
    red[wid][1] = n;
    red[wid][2] = r;
    red[wid][3] = t;
  }
  __syncthreads();

  if (threadIdx.x == 0) {
    float cc = 0.f, nn = 0.f, rr = 0.f, tt = 0.f;
#pragma unroll
    for (int w = 0; w < 4; ++w) {
      cc += red[w][0];
      nn += red[w][1];
      rr += red[w][2];
      tt += red[w][3];
    }
    nn *= kLNoobj;
    rr *= kLCoord;
    out[0] = cc + nn + rr + tt;  // total
    out[1] = rr;                 // reg_loss
    out[2] = tt;                 // contain_loss
    out[3] = nn;                 // no_obj_loss
    out[4] = cc;                 // cls_loss
  }
}

extern "C" void kernel_launch(void* const* d_in, const int* in_sizes, int n_in,
                              void* d_out, int out_size, void* d_ws, size_t ws_size,
                              hipStream_t stream) {
  const float* pred = (const float*)d_in[0];
  const float* tbox = (const float*)d_in[1];
  const float* tcls = (const float*)d_in[2];
  const int*   mask = (const int*)d_in[3];
  float* out = (float*)d_out;
  float* ws  = (float*)d_ws;

  const int ncells = in_sizes[3];              // N*S*S
  const int grid   = (ncells + kTile - 1) / kTile;

  yolo_partial_kernel<<<grid, 256, 0, stream>>>(pred, tbox, tcls, mask, ws, ncells);
  yolo_final_kernel<<<1, 256, 0, stream>>>(ws, grid, out);
}

// Round 8
// 34.602 us; speedup vs baseline: 3.7706x; 1.0046x over previous
//
#include <hip/hip_runtime.h>

// YOLO loss, two-stage reduction, async LDS staging, 128-cell tiles.
// R1: same-line atomics serialize -> two-stage plain stores (219->38us).
// R2: 120B-stride loads -> LDS tile staging (38->35us).
// R3: best-class structure (35.3us); latency-bound, not BW-bound.
// R4: inline per-float classify regressed (43.8us) -> VALU bloat.
// R5: source-level reg batching sunk by compiler -> neutral.
// R6: fused last-block atomic tail = +106us serialization. Never again.
// R7: global_load_lds staging: neutral (34.8us) -> staging MLP wasn't binding.
// R8: tile 256->128 cells (LDS 31.5->15.9KB): 5->8 blocks/CU = 32/32 waves.
//     One isolated change targeting occupancy/latency-hiding capacity.
//
// d_in[0] pred_tensor  f32 [N,S,S,30]
// d_in[1] target_boxes f32 [N,S,S,4]
// d_in[2] target_cls   f32 [N,S,S,20]
// d_in[3] has_object_map bool -> int32 [N,S,S]
// d_out: (total, reg, contain, noobj, cls) f32[5]

namespace {
constexpr float kLCoord = 5.0f;
constexpr float kLNoobj = 0.5f;
constexpr float kInvS   = 1.0f / 14.0f;
constexpr int   kTile   = 128;    // cells per block; 802816 = 6272*128 exact
}

__device__ __forceinline__ void async_cp16(const float4* g, float4* l) {
  __builtin_amdgcn_global_load_lds(
      (const __attribute__((address_space(1))) void*)g,
      (__attribute__((address_space(3))) void*)l,
      16, 0, 0);
}

__global__ __launch_bounds__(256) void yolo_partial_kernel(
    const float* __restrict__ pred,
    const float* __restrict__ tbox,
    const float* __restrict__ tcls,
    const int*   __restrict__ mask,
    float* __restrict__ ws,
    int ncells)
{
  __shared__ float lds_pred[kTile * 30];   // 15 KB linear, cell-major
  __shared__ int   lds_mask[kTile];        // 0.5 KB
  __shared__ float red[4][4];

  const int tid  = threadIdx.x;
  const int base = blockIdx.x * kTile;
  const int tile_cells = min(kTile, ncells - base);

  float cls_l = 0.f, noobj_l = 0.f, reg_l = 0.f, cont_l = 0.f;

  // ---- Phase A0: mask to LDS (coalesced; tid<128 only) ----
  int m_reg = 0;
  if (tid < kTile) {
    m_reg = (tid < tile_cells) ? mask[base + tid] : 0;
    lds_mask[tid] = m_reg;
  }

  // ---- Phase A1: async stage pred tile (960 float4 = 15KB) ----
  // 3 full wave-rounds + 192 (waves 0-2 full). Back-to-back issue, no VGPR
  // round-trip; the barrier's vmcnt(0) drains once.
  {
    const float4* src4 = reinterpret_cast<const float4*>(pred + (long)base * 30);
    float4* dst4 = reinterpret_cast<float4*>(lds_pred);
    if (tile_cells == kTile) {           // exact-tiling fast path (always here)
#pragma unroll
      for (int k = 0; k < 3; ++k)
        async_cp16(src4 + (tid + k * 256), dst4 + (tid + k * 256));
      if (tid < 192)                      // waves 0,1,2 whole
        async_cp16(src4 + (tid + 768), dst4 + (tid + 768));
    } else {
      const int nfl = tile_cells * 30;
      const int nf4 = nfl >> 2;
      for (int i = tid; i < nf4; i += 256) dst4[i] = src4[i];
      for (int f = (nf4 << 2) + tid; f < nfl; f += 256)
        lds_pred[f] = pred[(long)base * 30 + f];
    }
  }
  __syncthreads();   // drains vmcnt(0)+lgkm: pred tile + mask visible

  // ---- Phase B: per-cell box/IoU math (thread t <-> cell base+t, t<128) ----
  if (tid < tile_cells) {
    const float2* lp2 = reinterpret_cast<const float2*>(lds_pred + tid * 30);
    float pb[10];
#pragma unroll
    for (int i = 0; i < 5; ++i) {
      float2 v = lp2[i];
      pb[2 * i]     = v.x;
      pb[2 * i + 1] = v.y;
    }

    if (!m_reg) {
      noobj_l = pb[4] * pb[4] + pb[9] * pb[9];
    } else {
      float4 tb = *(reinterpret_cast<const float4*>(tbox) + (long)(base + tid));
      float tcx = tb.x * kInvS, tcy = tb.y * kInvS;
      float tx1 = tcx - 0.5f * tb.z;
      float ty1 = tcy - 0.5f * tb.w;
      float tx2 = tcx + 0.5f * tb.z;
      float ty2 = tcy + 0.5f * tb.w;
      float ta  = (tx2 - tx1) * (ty2 - ty1);

      float iou0, iou1;
#pragma unroll
      for (int b = 0; b < 2; ++b) {
        float qw = pb[5 * b + 2], qh = pb[5 * b + 3];
        float cx = pb[5 * b + 0] * kInvS, cy = pb[5 * b + 1] * kInvS;
        float px1 = cx - 0.5f * qw, py1 = cy - 0.5f * qh;
        float px2 = cx + 0.5f * qw, py2 = cy + 0.5f * qh;
        float lx = fmaxf(px1, tx1), ly = fmaxf(py1, ty1);
        float rx = fminf(px2, tx2), ry = fminf(py2, ty2);
        float w = fmaxf(rx - lx, 0.f), h = fmaxf(ry - ly, 0.f);
        float inter = w * h;
        float pa = (px2 - px1) * (py2 - py1);
        float v = inter / (pa + ta - inter);
        if (b == 0) iou0 = v; else iou1 = v;
      }

      // jnp.argmax -> first max on tie: box1 only on STRICT greater
      const bool sel = (iou1 > iou0);
      float biou = fmaxf(iou0, iou1);
      float bx = sel ? pb[5] : pb[0];
      float by = sel ? pb[6] : pb[1];
      float bw = sel ? pb[7] : pb[2];
      float bh = sel ? pb[8] : pb[3];
      float bc = sel ? pb[9] : pb[4];

      float dx = bx - tb.x, dy = by - tb.y;
      float dw = sqrtf(bw) - sqrtf(tb.z);
      float dh = sqrtf(bh) - sqrtf(tb.w);
      reg_l = dx * dx + dy * dy + dw * dw + dh * dh;   // *L_COORD in stage 2

      float dc = bc - biou;
      cont_l = dc * dc;
    }
  }

  // ---- Phase C: cls loss, element-parallel over the tile's tcls float4s ----
  // f4 index i in [0, tile_cells*5): cell = i/5, channels 10+4*(i%5)..+3.
  {
    const float4* tc = reinterpret_cast<const float4*>(tcls) + (long)base * 5;
    const int nf4c = tile_cells * 5;          // 640 when full
#pragma unroll
    for (int k = 0; k < 3; ++k) {
      const int i = tid + (k << 8);
      if (i < nf4c) {
        const int cl = i / 5;
        if (lds_mask[cl]) {                   // same-word broadcast across 5 lanes
          float4 t = tc[i];
          const float2* lp2 =
              reinterpret_cast<const float2*>(lds_pred + cl * 30 + 10 + ((i - cl * 5) << 2));
          float2 a0 = lp2[0], a1 = lp2[1];
          float c0 = a0.x - t.x;
          float c1 = a0.y - t.y;
          float c2 = a1.x - t.z;
          float c3 = a1.y - t.w;
          cls_l += c0 * c0 + c1 * c1 + c2 * c2 + c3 * c3;
        }
      }
    }
  }

  // ---- wave64 reduction ----
#pragma unroll
  for (int off = 32; off > 0; off >>= 1) {
    cls_l   += __shfl_down(cls_l,   off, 64);
    noobj_l += __shfl_down(noobj_l, off, 64);
    reg_l   += __shfl_down(reg_l,   off, 64);
    cont_l  += __shfl_down(cont_l,  off, 64);
  }

  const int lane = tid & 63;
  const int wid  = tid >> 6;
  if (lane == 0) {
    red[wid][0] = cls_l;
    red[wid][1] = noobj_l;
    red[wid][2] = reg_l;
    red[wid][3] = cont_l;
  }
  __syncthreads();

  if (tid == 0) {
    float c = 0.f, n = 0.f, r = 0.f, t = 0.f;
#pragma unroll
    for (int w = 0; w < 4; ++w) {
      c += red[w][0];
      n += red[w][1];
      r += red[w][2];
      t += red[w][3];
    }
    *(reinterpret_cast<float4*>(ws) + blockIdx.x) = make_float4(c, n, r, t);
  }
}

__global__ __launch_bounds__(1024) void yolo_final_kernel(
    const float* __restrict__ ws, int nparts, float* __restrict__ out)
{
  float c = 0.f, n = 0.f, r = 0.f, t = 0.f;
  for (int i = threadIdx.x; i < nparts; i += 1024) {
    float4 v = *(reinterpret_cast<const float4*>(ws) + i);
    c += v.x;
    n += v.y;
    r += v.z;
    t += v.w;
  }

#pragma unroll
  for (int off = 32; off > 0; off >>= 1) {
    c += __shfl_down(c, off, 64);
    n += __shfl_down(n, off, 64);
    r += __shfl_down(r, off, 64);
    t += __shfl_down(t, off, 64);
  }

  __shared__ float red[16][4];
  const int lane = threadIdx.x & 63;
  const int wid  = threadIdx.x >> 6;
  if (lane == 0) {
    red[wid][0] = c;
    red[wid][1] = n;
    red[wid][2] = r;
    red[wid][3] = t;
  }
  __syncthreads();

  if (threadIdx.x == 0) {
    float cc = 0.f, nn = 0.f, rr = 0.f, tt = 0.f;
#pragma unroll
    for (int w = 0; w < 16; ++w) {
      cc += red[w][0];
      nn += red[w][1];
      rr += red[w][2];
      tt += red[w][3];
    }
    nn *= kLNoobj;
    rr *= kLCoord;
    out[0] = cc + nn + rr + tt;  // total
    out[1] = rr;                 // reg_loss
    out[2] = tt;                 // contain_loss
    out[3] = nn;                 // no_obj_loss
    out[4] = cc;                 // cls_loss
  }
}

extern "C" void kernel_launch(void* const* d_in, const int* in_sizes, int n_in,
                              void* d_out, int out_size, void* d_ws, size_t ws_size,
                              hipStream_t stream) {
  const float* pred = (const float*)d_in[0];
  const float* tbox = (const float*)d_in[1];
  const float* tcls = (const float*)d_in[2];
  const int*   mask = (const int*)d_in[3];
  float* out = (float*)d_out;
  float* ws  = (float*)d_ws;

  const int ncells = in_sizes[3];              // N*S*S
  const int grid   = (ncells + kTile - 1) / kTile;

  yolo_partial_kernel<<<grid, 256, 0, stream>>>(pred, tbox, tcls, mask, ws, ncells);
  yolo_final_kernel<<<1, 1024, 0, stream>>>(ws, grid, out);
}